// Round 1
// baseline (348.238 us; speedup 1.0000x reference)
//
#include <hip/hip_runtime.h>

// Epsilon-greedy action selection.
//   q_vals:       [BATCH, N_ACTIONS] f32
//   rand_u:       [BATCH] f32
//   rand_actions: [BATCH] i32
//   out:          [BATCH] i32 = rand_u < eps ? rand_actions : argmax(q_vals, axis=1)
//
// Strategy: one 64-lane wave per row. Each lane issues two coalesced float4
// loads (16B/lane x 64 lanes = 1KiB contiguous per instruction), lane-local
// argmax over its 8 elements in ascending-index order (strict '>' preserves
// the first-max tie-break of jnp.argmax), then a 6-step shfl_xor butterfly
// reduction ordered by (value desc, index asc).

#define N_ACTIONS 512
#define EPSILON 0.05f
#define ROWS_PER_BLOCK 4  // 256 threads / 64 lanes

__global__ __launch_bounds__(256) void
SelectAction_64862596104471_kernel(const float* __restrict__ q_vals,
                                   const float* __restrict__ rand_u,
                                   const int* __restrict__ rand_actions,
                                   int* __restrict__ out,
                                   int batch) {
    const int wave = threadIdx.x >> 6;   // 0..3
    const int lane = threadIdx.x & 63;   // 0..63
    const long long row = (long long)blockIdx.x * ROWS_PER_BLOCK + wave;
    if (row >= batch) return;

    const float4* qrow = (const float4*)(q_vals + row * (long long)N_ACTIONS);

    // Two coalesced 16B loads per lane: elements [4*lane, 4*lane+3] and
    // [256 + 4*lane, 256 + 4*lane + 3].
    float4 a = qrow[lane];
    float4 b = qrow[lane + 64];

    // Lane-local argmax in ascending element-index order; strict '>' keeps
    // the lowest index on ties (jnp.argmax semantics).
    float best = a.x;
    int bidx = 4 * lane;
    if (a.y > best) { best = a.y; bidx = 4 * lane + 1; }
    if (a.z > best) { best = a.z; bidx = 4 * lane + 2; }
    if (a.w > best) { best = a.w; bidx = 4 * lane + 3; }
    if (b.x > best) { best = b.x; bidx = 256 + 4 * lane; }
    if (b.y > best) { best = b.y; bidx = 256 + 4 * lane + 1; }
    if (b.z > best) { best = b.z; bidx = 256 + 4 * lane + 2; }
    if (b.w > best) { best = b.w; bidx = 256 + 4 * lane + 3; }

    // 64-lane butterfly reduction: prefer higher value; on exact tie prefer
    // the lower element index.
    #pragma unroll
    for (int off = 32; off > 0; off >>= 1) {
        float oval = __shfl_xor(best, off, 64);
        int oidx = __shfl_xor(bidx, off, 64);
        if (oval > best || (oval == best && oidx < bidx)) {
            best = oval;
            bidx = oidx;
        }
    }

    if (lane == 0) {
        const float u = rand_u[row];
        const int ra = rand_actions[row];
        out[row] = (u < EPSILON) ? ra : bidx;
    }
}

extern "C" void kernel_launch(void* const* d_in, const int* in_sizes, int n_in,
                              void* d_out, int out_size, void* d_ws, size_t ws_size,
                              hipStream_t stream) {
    const float* q_vals = (const float*)d_in[0];
    const float* rand_u = (const float*)d_in[1];
    const int* rand_actions = (const int*)d_in[2];
    int* out = (int*)d_out;

    const int batch = in_sizes[1];  // rand_u element count == BATCH

    const int blocks = (batch + ROWS_PER_BLOCK - 1) / ROWS_PER_BLOCK;
    SelectAction_64862596104471_kernel<<<blocks, 256, 0, stream>>>(
        q_vals, rand_u, rand_actions, out, batch);
}